// Round 1
// baseline (1616.833 us; speedup 1.0000x reference)
//
#include <hip/hip_runtime.h>
#include <hip/hip_bf16.h>

#define DIM 384
#define HEADS 6
#define HD 64
#define LPIX 3136
#define HS 56
#define NPATCH 784
#define NF 392
#define SEQ 1569          // 1 + 392*4
#define BROWS 1568
#define HEXP 24
#define PR 96
#define HID 1536
#define SCALE 0.125f
#define SS 2461761        // 1569*1569
#define EPSV 1e-5f

// ---------------- conv (depthwise 3x3 + bias + residual), writes patch-token layout ----------------
__global__ __launch_bounds__(384) void conv_kernel(const float* __restrict__ x,
                                                   const float* __restrict__ cw,
                                                   const float* __restrict__ cb,
                                                   float* __restrict__ x1) {
    int l = blockIdx.x, c = threadIdx.x;
    int hh = l / HS, ww = l % HS;
    float acc = x[(long)l * DIM + c] + cb[c];
    #pragma unroll
    for (int kh = 0; kh < 3; kh++) {
        int h2 = hh + kh - 1;
        if (h2 < 0 || h2 >= HS) continue;
        #pragma unroll
        for (int kw = 0; kw < 3; kw++) {
            int w2 = ww + kw - 1;
            if (w2 < 0 || w2 >= HS) continue;
            acc += x[((long)h2 * HS + w2) * DIM + c] * cw[c * 9 + kh * 3 + kw];
        }
    }
    int p = (hh >> 1) * 28 + (ww >> 1);
    int t = ((hh & 1) << 1) | (ww & 1);
    x1[(long)(p * 4 + t) * DIM + c] = acc;
}

// ---------------- per-patch means ----------------
__global__ __launch_bounds__(256) void means_kernel(const float* __restrict__ x1, float* __restrict__ means) {
    int p = blockIdx.x, tid = threadIdx.x;
    __shared__ float red[256];
    float s = 0.f;
    for (int i = tid; i < 1536; i += 256) s += x1[(long)p * 1536 + i];
    red[tid] = s; __syncthreads();
    for (int k = 128; k > 0; k >>= 1) { if (tid < k) red[tid] += red[tid + k]; __syncthreads(); }
    if (tid == 0) means[p] = red[0] / 1536.f;
}

// ---------------- rank-based partition (stable descending argsort semantics) ----------------
__global__ void partition_kernel(const float* __restrict__ means, int* __restrict__ isfg,
                                 int* __restrict__ pos, int* __restrict__ fgmap, int* __restrict__ bgmap) {
    __shared__ float m_s[NPATCH];
    __shared__ unsigned char flag_s[NPATCH];
    int tid = threadIdx.x;
    for (int p = tid; p < NPATCH; p += blockDim.x) m_s[p] = means[p];
    __syncthreads();
    for (int p = tid; p < NPATCH; p += blockDim.x) {
        float m = m_s[p];
        int rank = 0;
        for (int q = 0; q < NPATCH; q++) {
            float mq = m_s[q];
            rank += (mq > m) || (mq == m && q < p);
        }
        flag_s[p] = (rank < NF) ? 1 : 0;
    }
    __syncthreads();
    for (int p = tid; p < NPATCH; p += blockDim.x) {
        int f = flag_s[p];
        int cnt = 0;
        for (int q = 0; q < p; q++) cnt += (flag_s[q] == f);
        isfg[p] = f; pos[p] = cnt;
        if (f) fgmap[cnt] = p; else bgmap[cnt] = p;
    }
}

// ---------------- gather foreground (with qa row 0) and background ----------------
__global__ __launch_bounds__(384) void gather_kernel(const float* __restrict__ x1, const float* __restrict__ qa,
                                                     const int* __restrict__ fgmap, const int* __restrict__ bgmap,
                                                     float* __restrict__ Xmsa, float* __restrict__ B) {
    int c = threadIdx.x;
    int bid = blockIdx.x;
    if (bid == 0) { Xmsa[c] = qa[c]; return; }
    if (bid <= BROWS) {
        int r = bid - 1;
        int src = fgmap[r >> 2] * 4 + (r & 3);
        Xmsa[(long)bid * DIM + c] = x1[(long)src * DIM + c];
    } else {
        int r = bid - SEQ;
        int src = bgmap[r >> 2] * 4 + (r & 3);
        B[(long)r * DIM + c] = x1[(long)src * DIM + c];
    }
}

// ---------------- generic tiled GEMM: C = alpha*A@op(W) + bias (+resid) (+silu) ----------------
// OPB=1: W is N x K (row-major), compute A@W^T.  OPB=0: W is K x N.
template<int OPB, int ACT>
__global__ __launch_bounds__(256) void gemm_kernel(
    const float* __restrict__ A, int lda, long long sA,
    const float* __restrict__ W, int ldw, long long sW,
    const float* __restrict__ bias,
    const float* __restrict__ resid, int ldr,
    float* __restrict__ C, int ldc, long long sC,
    int M, int N, int K, float alpha) {
    int bz = blockIdx.z;
    A += (long long)bz * sA; W += (long long)bz * sW; C += (long long)bz * sC;
    __shared__ float As[16][65];
    __shared__ float Bs[16][65];
    int tid = threadIdx.x;
    int tx = tid % 16, ty = tid / 16;
    int m0 = blockIdx.y * 64, n0 = blockIdx.x * 64;
    float acc[4][4] = {};
    for (int k0 = 0; k0 < K; k0 += 16) {
        {
            int i = tid >> 2;
            int kk = (tid & 3) << 2;
            int m = m0 + i;
            #pragma unroll
            for (int j = 0; j < 4; j++) {
                int k = k0 + kk + j;
                As[kk + j][i] = (m < M && k < K) ? A[(long long)m * lda + k] : 0.f;
            }
        }
        if (OPB == 1) {
            int i = tid >> 2;
            int kk = (tid & 3) << 2;
            int n = n0 + i;
            #pragma unroll
            for (int j = 0; j < 4; j++) {
                int k = k0 + kk + j;
                Bs[kk + j][i] = (n < N && k < K) ? W[(long long)n * ldw + k] : 0.f;
            }
        } else {
            int kk = tid >> 4;
            int nn = (tid & 15) << 2;
            int k = k0 + kk;
            #pragma unroll
            for (int j = 0; j < 4; j++) {
                int n = n0 + nn + j;
                Bs[kk][nn + j] = (k < K && n < N) ? W[(long long)k * ldw + n] : 0.f;
            }
        }
        __syncthreads();
        #pragma unroll
        for (int kk = 0; kk < 16; kk++) {
            float av[4], bv[4];
            #pragma unroll
            for (int i = 0; i < 4; i++) av[i] = As[kk][ty * 4 + i];
            #pragma unroll
            for (int j = 0; j < 4; j++) bv[j] = Bs[kk][tx * 4 + j];
            #pragma unroll
            for (int i = 0; i < 4; i++)
                #pragma unroll
                for (int j = 0; j < 4; j++)
                    acc[i][j] += av[i] * bv[j];
        }
        __syncthreads();
    }
    #pragma unroll
    for (int i = 0; i < 4; i++) {
        int m = m0 + ty * 4 + i;
        if (m >= M) continue;
        #pragma unroll
        for (int j = 0; j < 4; j++) {
            int n = n0 + tx * 4 + j;
            if (n >= N) continue;
            float v = acc[i][j] * alpha;
            if (bias) v += bias[n];
            if (ACT == 1) v = v / (1.f + expf(-v));
            if (resid) v += resid[(long long)m * ldr + n];
            C[(long long)m * ldc + n] = v;
        }
    }
}

// ---------------- modulated-attention transform: S plane -> A2 plane, in place, one block per q ----------------
__global__ __launch_bounds__(384) void modattn_kernel(float* __restrict__ S,
                                                      const float* __restrict__ ap1_w, const float* __restrict__ ap1_b,
                                                      const float* __restrict__ ap2_w, const float* __restrict__ ap2_b) {
    int q = blockIdx.x, tid = threadIdx.x;
    __shared__ float s_lds[6 * SEQ];
    __shared__ float red[384];
    __shared__ float w1s[HEXP * 6], w2s[6 * HEXP], b1s[HEXP], b2s[6];
    if (tid < HEXP * 6) { w1s[tid] = ap1_w[tid]; w2s[tid] = ap2_w[tid]; }
    if (tid < HEXP) b1s[tid] = ap1_b[tid];
    if (tid < 6) b2s[tid] = ap2_b[tid];
    for (int h = 0; h < 6; h++)
        for (int k = tid; k < SEQ; k += 384)
            s_lds[h * SEQ + k] = S[(long long)h * SS + (long long)q * SEQ + k];
    __syncthreads();
    int nk = (tid + 4 * 384 < SEQ) ? 5 : 4;
    float a2r[5][6];
    for (int j = 0; j < 5; j++)
        #pragma unroll
        for (int h = 0; h < 6; h++) a2r[j][h] = b2s[h];
    float a1v[5];
    for (int e = 0; e < HEXP; e++) {
        float lmax = -1e30f;
        for (int j = 0; j < nk; j++) {
            int k = tid + j * 384;
            float a = b1s[e];
            #pragma unroll
            for (int h = 0; h < 6; h++) a += s_lds[h * SEQ + k] * w1s[e * 6 + h];
            a1v[j] = a; lmax = fmaxf(lmax, a);
        }
        red[tid] = lmax; __syncthreads();
        if (tid < 128) red[tid] = fmaxf(red[tid], fmaxf(red[tid + 128], red[tid + 256]));
        __syncthreads();
        for (int s2 = 64; s2 > 0; s2 >>= 1) { if (tid < s2) red[tid] = fmaxf(red[tid], red[tid + s2]); __syncthreads(); }
        float gmax = red[0]; __syncthreads();
        float lsum = 0.f;
        for (int j = 0; j < nk; j++) { float pe = expf(a1v[j] - gmax); a1v[j] = pe; lsum += pe; }
        red[tid] = lsum; __syncthreads();
        if (tid < 128) red[tid] += red[tid + 128] + red[tid + 256];
        __syncthreads();
        for (int s2 = 64; s2 > 0; s2 >>= 1) { if (tid < s2) red[tid] += red[tid + s2]; __syncthreads(); }
        float inv = 1.f / red[0]; __syncthreads();
        for (int j = 0; j < nk; j++) {
            float pr = a1v[j] * inv;
            #pragma unroll
            for (int h = 0; h < 6; h++) a2r[j][h] += pr * w2s[h * HEXP + e];
        }
    }
    for (int j = 0; j < nk; j++) {
        int k = tid + j * 384;
        #pragma unroll
        for (int h = 0; h < 6; h++)
            S[(long long)h * SS + (long long)q * SEQ + k] = a2r[j][h];
    }
}

// ---------------- single-query attention pooling (per head) ----------------
__global__ __launch_bounds__(256) void sqa_attn_kernel(const float* __restrict__ kv, const float* __restrict__ qa2,
                                                       float* __restrict__ x1h) {
    int h = blockIdx.x, tid = threadIdx.x;
    __shared__ float q_s[HD];
    __shared__ float l_s[BROWS];
    __shared__ float red[256];
    if (tid < HD) q_s[tid] = qa2[h * HD + tid];
    __syncthreads();
    float lmax = -1e30f;
    for (int s = tid; s < BROWS; s += 256) {
        const float* krow = kv + (long long)s * 768 + h * HD;
        float d = 0.f;
        for (int i = 0; i < HD; i++) d += krow[i] * q_s[i];
        d *= SCALE; l_s[s] = d; lmax = fmaxf(lmax, d);
    }
    red[tid] = lmax; __syncthreads();
    for (int s = 128; s > 0; s >>= 1) { if (tid < s) red[tid] = fmaxf(red[tid], red[tid + s]); __syncthreads(); }
    float gmax = red[0]; __syncthreads();
    float lsum = 0.f;
    for (int s = tid; s < BROWS; s += 256) { float p = expf(l_s[s] - gmax); l_s[s] = p; lsum += p; }
    red[tid] = lsum; __syncthreads();
    for (int s = 128; s > 0; s >>= 1) { if (tid < s) red[tid] += red[tid + s]; __syncthreads(); }
    float inv = 1.f / red[0]; __syncthreads();
    int d = tid & 63, g = tid >> 6;
    float acc = 0.f;
    for (int s = g; s < BROWS; s += 4) acc += l_s[s] * kv[(long long)s * 768 + 384 + h * HD + d];
    red[tid] = acc; __syncthreads();
    if (tid < HD) x1h[h * HD + d] = (red[d] + red[64 + d] + red[128 + d] + red[192 + d]) * inv;
}

// ---------------- sqa mlp: sp1 -> LN -> relu -> sp2 ----------------
__global__ __launch_bounds__(384) void sqa_mlp_kernel(const float* __restrict__ x1h,
                                                      const float* __restrict__ sp1_w, const float* __restrict__ sp1_b,
                                                      const float* __restrict__ pn_w, const float* __restrict__ pn_b,
                                                      const float* __restrict__ sp2_w, const float* __restrict__ sp2_b,
                                                      float* __restrict__ z) {
    __shared__ float y_s[PR];
    __shared__ float x_s[DIM];
    __shared__ float mv[2];
    int tid = threadIdx.x;
    x_s[tid] = x1h[tid];
    __syncthreads();
    if (tid < PR) {
        float a = sp1_b[tid];
        for (int c = 0; c < DIM; c++) a += sp1_w[tid * DIM + c] * x_s[c];
        y_s[tid] = a;
    }
    __syncthreads();
    if (tid == 0) {
        float m = 0.f; for (int i = 0; i < PR; i++) m += y_s[i]; m /= (float)PR;
        float v = 0.f; for (int i = 0; i < PR; i++) { float d = y_s[i] - m; v += d * d; } v /= (float)PR;
        mv[0] = m; mv[1] = rsqrtf(v + EPSV);
    }
    __syncthreads();
    if (tid < PR) {
        float yn = (y_s[tid] - mv[0]) * mv[1] * pn_w[tid] + pn_b[tid];
        y_s[tid] = fmaxf(yn, 0.f);
    }
    __syncthreads();
    float a = sp2_b[tid];
    for (int j = 0; j < PR; j++) a += sp2_w[tid * PR + j] * y_s[j];
    z[tid] = a;
}

// ---------------- scatter + unpatchify + LN1 + residual + LN2 ----------------
__global__ __launch_bounds__(384) void scatter_ln_kernel(
    const float* __restrict__ x, const float* __restrict__ mpout, const float* __restrict__ B,
    const float* __restrict__ z, const int* __restrict__ isfg, const int* __restrict__ pos,
    const float* __restrict__ n1w, const float* __restrict__ n1b,
    const float* __restrict__ n2w, const float* __restrict__ n2b,
    float* __restrict__ x_mid, float* __restrict__ h_norm) {
    int l = blockIdx.x, c = threadIdx.x;
    int hh = l / HS, ww = l % HS;
    int p = (hh >> 1) * 28 + (ww >> 1);
    int t = ((hh & 1) << 1) | (ww & 1);
    float v;
    if (isfg[p]) v = mpout[(long long)(1 + pos[p] * 4 + t) * DIM + c];
    else v = B[(long long)(pos[p] * 4 + t) * DIM + c] + z[c];
    __shared__ float red[384], red2[384];
    red[c] = v; red2[c] = v * v; __syncthreads();
    if (c < 128) { red[c] += red[c + 128] + red[c + 256]; red2[c] += red2[c + 128] + red2[c + 256]; }
    __syncthreads();
    for (int s = 64; s > 0; s >>= 1) { if (c < s) { red[c] += red[c + s]; red2[c] += red2[c + s]; } __syncthreads(); }
    float mean = red[0] / (float)DIM;
    float var = red2[0] / (float)DIM - mean * mean;
    __syncthreads();
    float xm = x[(long long)l * DIM + c] + (v - mean) * rsqrtf(var + EPSV) * n1w[c] + n1b[c];
    x_mid[(long long)l * DIM + c] = xm;
    red[c] = xm; red2[c] = xm * xm; __syncthreads();
    if (c < 128) { red[c] += red[c + 128] + red[c + 256]; red2[c] += red2[c + 128] + red2[c + 256]; }
    __syncthreads();
    for (int s = 64; s > 0; s >>= 1) { if (c < s) { red[c] += red[c + s]; red2[c] += red2[c + s]; } __syncthreads(); }
    float m2 = red[0] / (float)DIM;
    float v2 = red2[0] / (float)DIM - m2 * m2;
    h_norm[(long long)l * DIM + c] = (xm - m2) * rsqrtf(v2 + EPSV) * n2w[c] + n2b[c];
}

__global__ void copy_qa2_kernel(const float* __restrict__ mp, float* __restrict__ dst) {
    dst[threadIdx.x] = mp[threadIdx.x];
}

extern "C" void kernel_launch(void* const* d_in, const int* in_sizes, int n_in,
                              void* d_out, int out_size, void* d_ws, size_t ws_size,
                              hipStream_t stream) {
    const float* x       = (const float*)d_in[0];
    const float* qa      = (const float*)d_in[1];
    const float* conv_w  = (const float*)d_in[2];
    const float* conv_b  = (const float*)d_in[3];
    const float* n1w     = (const float*)d_in[4];
    const float* n1b     = (const float*)d_in[5];
    const float* n2w     = (const float*)d_in[6];
    const float* n2b     = (const float*)d_in[7];
    const float* qkv_w   = (const float*)d_in[8];
    const float* qkv_b   = (const float*)d_in[9];
    const float* mproj_w = (const float*)d_in[10];
    const float* mproj_b = (const float*)d_in[11];
    const float* ap1_w   = (const float*)d_in[12];
    const float* ap1_b   = (const float*)d_in[13];
    const float* ap2_w   = (const float*)d_in[14];
    const float* ap2_b   = (const float*)d_in[15];
    const float* kv_w    = (const float*)d_in[16];
    const float* kv_b    = (const float*)d_in[17];
    const float* sp1_w   = (const float*)d_in[18];
    const float* sp1_b   = (const float*)d_in[19];
    const float* sp2_w   = (const float*)d_in[20];
    const float* sp2_b   = (const float*)d_in[21];
    const float* pn_w    = (const float*)d_in[22];
    const float* pn_b    = (const float*)d_in[23];
    const float* fc1_w   = (const float*)d_in[24];
    const float* fc1_b   = (const float*)d_in[25];
    const float* fc2_w   = (const float*)d_in[26];
    const float* fc2_b   = (const float*)d_in[27];
    float* out = (float*)d_out;
    float* ws  = (float*)d_ws;

    // workspace layout (floats), with lifetime-safe aliasing
    float* x1_arr = ws;                    // 1204224   (patch-token conv output; later h_norm)
    float* Xmsa   = ws + 1204224;          // 602496    (MSA input; later attn_out)
    float* Bmat   = ws + 1806720;          // 602112
    float* qkvb   = ws + 2408832;          // 1807488   (qkv; later kv_out)
    float* Sbuf   = ws + 4216320;          // 14770566  (S / A2; later fc1 activations)
    float* mpout  = ws + 18986944;         // 602496
    float* xmid   = ws + 19589440;         // 1204224
    float* means  = ws + 20793664;         // 784
    float* x1h    = ws + 20794448;         // 384
    float* zvec   = ws + 20794832;         // 384
    int*   isfg   = (int*)(ws + 20795216); // 784
    int*   pos    = (int*)(ws + 20796000); // 784
    int*   fgmap  = (int*)(ws + 20796784); // 392
    int*   bgmap  = (int*)(ws + 20797176); // 392
    float* attn_out = Xmsa;
    float* kv_out   = qkvb;
    float* h_norm   = x1_arr;
    float* h_act    = Sbuf;

    conv_kernel<<<LPIX, 384, 0, stream>>>(x, conv_w, conv_b, x1_arr);
    means_kernel<<<NPATCH, 256, 0, stream>>>(x1_arr, means);
    partition_kernel<<<1, 256, 0, stream>>>(means, isfg, pos, fgmap, bgmap);
    gather_kernel<<<SEQ + BROWS, 384, 0, stream>>>(x1_arr, qa, fgmap, bgmap, Xmsa, Bmat);

    { // qkv: (1569x384) @ (1152x384)^T
        dim3 g((1152 + 63) / 64, (SEQ + 63) / 64, 1);
        gemm_kernel<1, 0><<<g, 256, 0, stream>>>(Xmsa, DIM, 0, qkv_w, DIM, 0, qkv_b,
                                                 nullptr, 0, qkvb, 1152, 0, SEQ, 1152, DIM, 1.f);
    }
    { // S[h] = SCALE * q @ k^T, batched over 6 heads
        dim3 g((SEQ + 63) / 64, (SEQ + 63) / 64, 6);
        gemm_kernel<1, 0><<<g, 256, 0, stream>>>(qkvb, 1152, 64, qkvb + 384, 1152, 64, nullptr,
                                                 nullptr, 0, Sbuf, SEQ, (long long)SS, SEQ, SEQ, HD, SCALE);
    }
    modattn_kernel<<<SEQ, 384, 0, stream>>>(Sbuf, ap1_w, ap1_b, ap2_w, ap2_b);
    { // PV: out[h] = A2[h] @ V[h], batched
        dim3 g(1, (SEQ + 63) / 64, 6);
        gemm_kernel<0, 0><<<g, 256, 0, stream>>>(Sbuf, SEQ, (long long)SS, qkvb + 768, 1152, 64, nullptr,
                                                 nullptr, 0, attn_out, DIM, 64, SEQ, HD, SEQ, 1.f);
    }
    { // mproj
        dim3 g(6, (SEQ + 63) / 64, 1);
        gemm_kernel<1, 0><<<g, 256, 0, stream>>>(attn_out, DIM, 0, mproj_w, DIM, 0, mproj_b,
                                                 nullptr, 0, mpout, DIM, 0, SEQ, DIM, DIM, 1.f);
    }
    { // kv for sqa
        dim3 g(12, (BROWS + 63) / 64, 1);
        gemm_kernel<1, 0><<<g, 256, 0, stream>>>(Bmat, DIM, 0, kv_w, DIM, 0, kv_b,
                                                 nullptr, 0, kv_out, 768, 0, BROWS, 768, DIM, 1.f);
    }
    sqa_attn_kernel<<<HEADS, 256, 0, stream>>>(kv_out, mpout /* row 0 = qa2 */, x1h);
    sqa_mlp_kernel<<<1, 384, 0, stream>>>(x1h, sp1_w, sp1_b, pn_w, pn_b, sp2_w, sp2_b, zvec);
    scatter_ln_kernel<<<LPIX, 384, 0, stream>>>(x, mpout, Bmat, zvec, isfg, pos,
                                                n1w, n1b, n2w, n2b, xmid, h_norm);
    { // fc1 + silu
        dim3 g(HID / 64, LPIX / 64, 1);
        gemm_kernel<1, 1><<<g, 256, 0, stream>>>(h_norm, DIM, 0, fc1_w, DIM, 0, fc1_b,
                                                 nullptr, 0, h_act, HID, 0, LPIX, HID, DIM, 1.f);
    }
    { // fc2 + residual -> out
        dim3 g(DIM / 64, LPIX / 64, 1);
        gemm_kernel<1, 0><<<g, 256, 0, stream>>>(h_act, HID, 0, fc2_w, HID, 0, fc2_b,
                                                 xmid, DIM, out, DIM, 0, LPIX, DIM, HID, 1.f);
    }
    copy_qa2_kernel<<<1, 384, 0, stream>>>(mpout, out + (long long)LPIX * DIM);
}

// Round 2
// 1161.231 us; speedup vs baseline: 1.3923x; 1.3923x over previous
//
#include <hip/hip_runtime.h>
#include <hip/hip_bf16.h>

#define DIM 384
#define HEADS 6
#define HD 64
#define LPIX 3136
#define HS 56
#define NPATCH 784
#define NF 392
#define SEQ 1569          // 1 + 392*4
#define BROWS 1568
#define HEXP 24
#define PR 96
#define HID 1536
#define SCALE 0.125f
#define SS 2461761        // 1569*1569
#define EPSV 1e-5f

typedef short short8v __attribute__((ext_vector_type(8)));
typedef float f32x4 __attribute__((ext_vector_type(4)));
typedef unsigned short ushort;

__device__ __forceinline__ ushort f2b(float f) {
    __hip_bfloat16 h = __float2bfloat16(f);
    return reinterpret_cast<ushort&>(h);
}

// ---------------- weight fp32 -> bf16 conversion (5 segments in one kernel) ----------------
struct CvtSeg { const float* s; ushort* d; int n; };
__global__ __launch_bounds__(256) void cvt_kernel(CvtSeg a, CvtSeg b, CvtSeg c, CvtSeg d, CvtSeg e) {
    CvtSeg seg;
    switch (blockIdx.y) { case 0: seg = a; break; case 1: seg = b; break; case 2: seg = c; break;
                          case 3: seg = d; break; default: seg = e; break; }
    int idx = (blockIdx.x * 256 + threadIdx.x) * 8;
    if (idx >= seg.n) return;
    float4 f0 = *reinterpret_cast<const float4*>(seg.s + idx);
    float4 f1 = *reinterpret_cast<const float4*>(seg.s + idx + 4);
    ushort u[8] = { f2b(f0.x), f2b(f0.y), f2b(f0.z), f2b(f0.w),
                    f2b(f1.x), f2b(f1.y), f2b(f1.z), f2b(f1.w) };
    *reinterpret_cast<uint4*>(seg.d + idx) = *reinterpret_cast<uint4*>(u);
}

// ---------------- conv (depthwise 3x3 + bias + residual), writes patch-token layout ----------------
__global__ __launch_bounds__(384) void conv_kernel(const float* __restrict__ x,
                                                   const float* __restrict__ cw,
                                                   const float* __restrict__ cb,
                                                   float* __restrict__ x1) {
    int l = blockIdx.x, c = threadIdx.x;
    int hh = l / HS, ww = l % HS;
    float acc = x[(long)l * DIM + c] + cb[c];
    #pragma unroll
    for (int kh = 0; kh < 3; kh++) {
        int h2 = hh + kh - 1;
        if (h2 < 0 || h2 >= HS) continue;
        #pragma unroll
        for (int kw = 0; kw < 3; kw++) {
            int w2 = ww + kw - 1;
            if (w2 < 0 || w2 >= HS) continue;
            acc += x[((long)h2 * HS + w2) * DIM + c] * cw[c * 9 + kh * 3 + kw];
        }
    }
    int p = (hh >> 1) * 28 + (ww >> 1);
    int t = ((hh & 1) << 1) | (ww & 1);
    x1[(long)(p * 4 + t) * DIM + c] = acc;
}

// ---------------- per-patch means ----------------
__global__ __launch_bounds__(256) void means_kernel(const float* __restrict__ x1, float* __restrict__ means) {
    int p = blockIdx.x, tid = threadIdx.x;
    __shared__ float red[256];
    float s = 0.f;
    for (int i = tid; i < 1536; i += 256) s += x1[(long)p * 1536 + i];
    red[tid] = s; __syncthreads();
    for (int k = 128; k > 0; k >>= 1) { if (tid < k) red[tid] += red[tid + k]; __syncthreads(); }
    if (tid == 0) means[p] = red[0] / 1536.f;
}

// ---------------- rank flags (parallel over patches) ----------------
__global__ __launch_bounds__(256) void partition_flags_kernel(const float* __restrict__ means, int* __restrict__ flags) {
    int p = blockIdx.x * 256 + threadIdx.x;
    if (p >= NPATCH) return;
    float m = means[p];
    int rank = 0;
    for (int q = 0; q < NPATCH; q++) {
        float mq = means[q];
        rank += (mq > m) || (mq == m && q < p);
    }
    flags[p] = (rank < NF) ? 1 : 0;
}

// ---------------- compaction: prefix scan over flags ----------------
__global__ __launch_bounds__(256) void partition_compact_kernel(const int* __restrict__ flags, int* __restrict__ isfg,
                                                                int* __restrict__ pos, int* __restrict__ fgmap,
                                                                int* __restrict__ bgmap) {
    __shared__ int f_s[NPATCH];
    __shared__ int scan_s[256];
    int tid = threadIdx.x;
    for (int p = tid; p < NPATCH; p += 256) f_s[p] = flags[p];
    __syncthreads();
    int base = tid * 4, cnt = 0;
    #pragma unroll
    for (int i = 0; i < 4; i++) { int p = base + i; if (p < NPATCH) cnt += f_s[p]; }
    scan_s[tid] = cnt; __syncthreads();
    for (int off = 1; off < 256; off <<= 1) {
        int add = (tid >= off) ? scan_s[tid - off] : 0;
        __syncthreads();
        scan_s[tid] += add;
        __syncthreads();
    }
    int run = scan_s[tid] - cnt;  // exclusive fg count before this chunk
    for (int i = 0; i < 4; i++) {
        int p = base + i;
        if (p >= NPATCH) break;
        int f = f_s[p];
        if (f) { isfg[p] = 1; pos[p] = run; fgmap[run] = p; run++; }
        else   { isfg[p] = 0; pos[p] = p - run; bgmap[p - run] = p; }
    }
}

// ---------------- gather foreground (with qa row 0) and background ----------------
__global__ __launch_bounds__(384) void gather_kernel(const float* __restrict__ x1, const float* __restrict__ qa,
                                                     const int* __restrict__ fgmap, const int* __restrict__ bgmap,
                                                     ushort* __restrict__ Xmsa_bf, float* __restrict__ B,
                                                     ushort* __restrict__ B_bf) {
    int c = threadIdx.x;
    int bid = blockIdx.x;
    if (bid == 0) { Xmsa_bf[c] = f2b(qa[c]); return; }
    if (bid <= BROWS) {
        int r = bid - 1;
        int src = fgmap[r >> 2] * 4 + (r & 3);
        Xmsa_bf[(long)bid * DIM + c] = f2b(x1[(long)src * DIM + c]);
    } else {
        int r = bid - SEQ;
        int src = bgmap[r >> 2] * 4 + (r & 3);
        float v = x1[(long)src * DIM + c];
        B[(long)r * DIM + c] = v;
        B_bf[(long)r * DIM + c] = f2b(v);
    }
}

// ---------------- bf16 MFMA GEMM ----------------
// C = alpha * A @ op(B) + bias (+silu) (+resid). BM=128, BK=32.
// OPB=1: B is [N][K] bf16 (row-major, A@B^T). OPB=0: B is [K][N] bf16 (only BN=64).
// AF32=1: A is fp32, converted during staging. OUTBF=1: C stored bf16, else fp32.
template<int BN, int OPB, int ACT, int OUTBF, int AF32>
__global__ __launch_bounds__(256) void mgemm(
    const void* __restrict__ Av, int lda, long long sA,
    const ushort* __restrict__ B, int ldb, long long sB,
    const float* __restrict__ bias, const float* __restrict__ resid, int ldr,
    void* __restrict__ Cv, int ldc, long long sC,
    int M, int N, int K, float alpha) {
    constexpr int BM = 128, BK = 32, LDT = BK + 8;
    constexpr int WR = (BN == 128) ? 2 : 4;
    constexpr int WC = (BN == 128) ? 2 : 1;
    constexpr int MFR = BM / WR / 16;     // 4 (BN=128) or 2 (BN=64)
    constexpr int NFR = BN / WC / 16;     // 4
    __shared__ ushort As[BM * LDT];
    __shared__ ushort Bs[BN * LDT];
    int tid = threadIdx.x;
    int wid = tid >> 6, lane = tid & 63;
    int m0 = blockIdx.y * BM, n0 = blockIdx.x * BN;
    int bz = blockIdx.z;
    const ushort* A16 = (const ushort*)Av;
    const float* A32 = (const float*)Av;
    if (AF32) A32 += bz * sA; else A16 += bz * sA;
    B += bz * sB;
    int wm = (wid / WC) * (BM / WR);
    int wn = (wid % WC) * (BN / WC);
    f32x4 acc[MFR][NFR];
    #pragma unroll
    for (int mi = 0; mi < MFR; mi++)
        #pragma unroll
        for (int ni = 0; ni < NFR; ni++) acc[mi][ni] = (f32x4){0.f, 0.f, 0.f, 0.f};

    for (int k0 = 0; k0 < K; k0 += BK) {
        // ---- stage A ----
        if (AF32) {
            #pragma unroll
            for (int t = 0; t < 16; t++) {
                int elem = t * 256 + tid;            // 4096 = 128x32
                int row = elem >> 5, col = elem & 31;
                int gm = m0 + row, gk = k0 + col;
                As[row * LDT + col] = (gm < M && gk < K) ? f2b(A32[(long long)gm * lda + gk]) : (ushort)0;
            }
        } else {
            #pragma unroll
            for (int t = 0; t < 2; t++) {
                int chunk = tid + t * 256;
                int row = chunk >> 2, part = chunk & 3;
                int gm = m0 + row, gk = k0 + part * 8;
                ushort* dst = &As[row * LDT + part * 8];
                if (gm < M && gk + 8 <= K) {
                    *reinterpret_cast<uint4*>(dst) =
                        *reinterpret_cast<const uint4*>(&A16[(long long)gm * lda + gk]);
                } else {
                    #pragma unroll
                    for (int i = 0; i < 8; i++) {
                        int k = gk + i;
                        dst[i] = (gm < M && k < K) ? A16[(long long)gm * lda + k] : (ushort)0;
                    }
                }
            }
        }
        // ---- stage B ----
        if (OPB == 1) {
            constexpr int CH = BN * 4 / 256;
            #pragma unroll
            for (int t = 0; t < CH; t++) {
                int chunk = tid + t * 256;
                int row = chunk >> 2, part = chunk & 3;
                int gn = n0 + row, gk = k0 + part * 8;
                ushort* dst = &Bs[row * LDT + part * 8];
                if (gn < N && gk + 8 <= K) {
                    *reinterpret_cast<uint4*>(dst) =
                        *reinterpret_cast<const uint4*>(&B[(long long)gn * ldb + gk]);
                } else {
                    #pragma unroll
                    for (int i = 0; i < 8; i++) {
                        int k = gk + i;
                        dst[i] = (gn < N && k < K) ? B[(long long)gn * ldb + k] : (ushort)0;
                    }
                }
            }
        } else {
            // B is [K][N], BN==64: 32 x 64 tile, transpose into Bs[n][k]
            int kr = tid >> 3, nn = (tid & 7) * 8;
            int gk = k0 + kr;
            ushort vals[8];
            if (gk < K && n0 + nn + 8 <= N) {
                *reinterpret_cast<uint4*>(vals) =
                    *reinterpret_cast<const uint4*>(&B[(long long)gk * ldb + n0 + nn]);
            } else {
                #pragma unroll
                for (int i = 0; i < 8; i++) {
                    int gn = n0 + nn + i;
                    vals[i] = (gk < K && gn < N) ? B[(long long)gk * ldb + gn] : (ushort)0;
                }
            }
            #pragma unroll
            for (int i = 0; i < 8; i++) Bs[(nn + i) * LDT + kr] = vals[i];
        }
        __syncthreads();
        // ---- MFMA ----
        short8v a[MFR], b[NFR];
        #pragma unroll
        for (int mi = 0; mi < MFR; mi++)
            a[mi] = *reinterpret_cast<const short8v*>(&As[(wm + mi * 16 + (lane & 15)) * LDT + (lane >> 4) * 8]);
        #pragma unroll
        for (int ni = 0; ni < NFR; ni++)
            b[ni] = *reinterpret_cast<const short8v*>(&Bs[(wn + ni * 16 + (lane & 15)) * LDT + (lane >> 4) * 8]);
        #pragma unroll
        for (int mi = 0; mi < MFR; mi++)
            #pragma unroll
            for (int ni = 0; ni < NFR; ni++)
                acc[mi][ni] = __builtin_amdgcn_mfma_f32_16x16x32_bf16(a[mi], b[ni], acc[mi][ni], 0, 0, 0);
        __syncthreads();
    }
    // ---- epilogue ----
    ushort* C16 = (ushort*)Cv;
    float* C32 = (float*)Cv;
    #pragma unroll
    for (int mi = 0; mi < MFR; mi++) {
        #pragma unroll
        for (int j = 0; j < 4; j++) {
            int gm = m0 + wm + mi * 16 + (lane >> 4) * 4 + j;
            if (gm >= M) continue;
            #pragma unroll
            for (int ni = 0; ni < NFR; ni++) {
                int gn = n0 + wn + ni * 16 + (lane & 15);
                if (gn >= N) continue;
                float v = acc[mi][ni][j] * alpha;
                if (bias) v += bias[gn];
                if (ACT == 1) v = v / (1.f + expf(-v));
                if (resid) v += resid[(long long)gm * ldr + gn];
                long long ci = bz * sC + (long long)gm * ldc + gn;
                if (OUTBF) C16[ci] = f2b(v); else C32[ci] = v;
            }
        }
    }
}

// ---------------- modulated-attention transform: in-place on S (fp32), register-resident ----------------
__global__ __launch_bounds__(384) void modattn_kernel(float* __restrict__ S,
                                                      const float* __restrict__ ap1_w, const float* __restrict__ ap1_b,
                                                      const float* __restrict__ ap2_w, const float* __restrict__ ap2_b) {
    int q = blockIdx.x, tid = threadIdx.x;
    int wid = tid >> 6, lane = tid & 63;
    __shared__ float w1s[HEXP * 6], w2s[6 * HEXP], b1s[HEXP], b2s[6];
    __shared__ float wred[2][8], sred[2][8];
    if (tid < HEXP * 6) { w1s[tid] = ap1_w[tid]; w2s[tid] = ap2_w[tid]; }
    if (tid < HEXP) b1s[tid] = ap1_b[tid];
    if (tid < 6) b2s[tid] = ap2_b[tid];
    __syncthreads();
    int nk = (tid < 33) ? 5 : 4;    // k = tid + j*384 < 1569
    float sreg[5][6];
    long long qb = (long long)q * SEQ;
    #pragma unroll
    for (int h = 0; h < 6; h++) {
        const float* Sh = S + (long long)h * SS + qb;
        for (int j = 0; j < nk; j++) sreg[j][h] = Sh[tid + j * 384];
    }
    float a2r[5][6];
    for (int j = 0; j < nk; j++)
        #pragma unroll
        for (int h = 0; h < 6; h++) a2r[j][h] = b2s[h];
    float a1[5];
    for (int e = 0; e < HEXP; e++) {
        float mloc = -3.4e38f;
        for (int j = 0; j < nk; j++) {
            float a = b1s[e];
            #pragma unroll
            for (int h = 0; h < 6; h++) a += sreg[j][h] * w1s[e * 6 + h];
            a1[j] = a; mloc = fmaxf(mloc, a);
        }
        #pragma unroll
        for (int off = 32; off >= 1; off >>= 1) mloc = fmaxf(mloc, __shfl_xor(mloc, off));
        if (lane == 0) wred[e & 1][wid] = mloc;
        __syncthreads();
        float gmax = fmaxf(fmaxf(fmaxf(wred[e & 1][0], wred[e & 1][1]), fmaxf(wred[e & 1][2], wred[e & 1][3])),
                           fmaxf(wred[e & 1][4], wred[e & 1][5]));
        float sloc = 0.f;
        for (int j = 0; j < nk; j++) { float p = __expf(a1[j] - gmax); a1[j] = p; sloc += p; }
        #pragma unroll
        for (int off = 32; off >= 1; off >>= 1) sloc += __shfl_xor(sloc, off);
        if (lane == 0) sred[e & 1][wid] = sloc;
        __syncthreads();
        float tot = sred[e & 1][0] + sred[e & 1][1] + sred[e & 1][2] +
                    sred[e & 1][3] + sred[e & 1][4] + sred[e & 1][5];
        float inv = 1.f / tot;
        for (int j = 0; j < nk; j++) {
            float pr = a1[j] * inv;
            #pragma unroll
            for (int h = 0; h < 6; h++) a2r[j][h] += pr * w2s[h * HEXP + e];
        }
    }
    #pragma unroll
    for (int h = 0; h < 6; h++) {
        float* Sh = S + (long long)h * SS + qb;
        for (int j = 0; j < nk; j++) Sh[tid + j * 384] = a2r[j][h];
    }
}

// ---------------- single-query attention pooling (per head) ----------------
__global__ __launch_bounds__(256) void sqa_attn_kernel(const float* __restrict__ kv, const float* __restrict__ qa2,
                                                       float* __restrict__ x1h) {
    int h = blockIdx.x, tid = threadIdx.x;
    __shared__ float q_s[HD];
    __shared__ float l_s[BROWS];
    __shared__ float red[256];
    if (tid < HD) q_s[tid] = qa2[h * HD + tid];
    __syncthreads();
    float lmax = -1e30f;
    for (int s = tid; s < BROWS; s += 256) {
        const float* krow = kv + (long long)s * 768 + h * HD;
        float d = 0.f;
        for (int i = 0; i < HD; i++) d += krow[i] * q_s[i];
        d *= SCALE; l_s[s] = d; lmax = fmaxf(lmax, d);
    }
    red[tid] = lmax; __syncthreads();
    for (int s = 128; s > 0; s >>= 1) { if (tid < s) red[tid] = fmaxf(red[tid], red[tid + s]); __syncthreads(); }
    float gmax = red[0]; __syncthreads();
    float lsum = 0.f;
    for (int s = tid; s < BROWS; s += 256) { float p = __expf(l_s[s] - gmax); l_s[s] = p; lsum += p; }
    red[tid] = lsum; __syncthreads();
    for (int s = 128; s > 0; s >>= 1) { if (tid < s) red[tid] += red[tid + s]; __syncthreads(); }
    float inv = 1.f / red[0]; __syncthreads();
    int d = tid & 63, g = tid >> 6;
    float acc = 0.f;
    for (int s = g; s < BROWS; s += 4) acc += l_s[s] * kv[(long long)s * 768 + 384 + h * HD + d];
    red[tid] = acc; __syncthreads();
    if (tid < HD) x1h[h * HD + d] = (red[d] + red[64 + d] + red[128 + d] + red[192 + d]) * inv;
}

// ---------------- sqa mlp: sp1 -> LN -> relu -> sp2 ----------------
__global__ __launch_bounds__(384) void sqa_mlp_kernel(const float* __restrict__ x1h,
                                                      const float* __restrict__ sp1_w, const float* __restrict__ sp1_b,
                                                      const float* __restrict__ pn_w, const float* __restrict__ pn_b,
                                                      const float* __restrict__ sp2_w, const float* __restrict__ sp2_b,
                                                      float* __restrict__ z) {
    __shared__ float y_s[PR];
    __shared__ float x_s[DIM];
    __shared__ float mv[2];
    int tid = threadIdx.x;
    x_s[tid] = x1h[tid];
    __syncthreads();
    if (tid < PR) {
        float a = sp1_b[tid];
        for (int c = 0; c < DIM; c++) a += sp1_w[tid * DIM + c] * x_s[c];
        y_s[tid] = a;
    }
    __syncthreads();
    if (tid == 0) {
        float m = 0.f; for (int i = 0; i < PR; i++) m += y_s[i]; m /= (float)PR;
        float v = 0.f; for (int i = 0; i < PR; i++) { float d = y_s[i] - m; v += d * d; } v /= (float)PR;
        mv[0] = m; mv[1] = rsqrtf(v + EPSV);
    }
    __syncthreads();
    if (tid < PR) {
        float yn = (y_s[tid] - mv[0]) * mv[1] * pn_w[tid] + pn_b[tid];
        y_s[tid] = fmaxf(yn, 0.f);
    }
    __syncthreads();
    float a = sp2_b[tid];
    for (int j = 0; j < PR; j++) a += sp2_w[tid * PR + j] * y_s[j];
    z[tid] = a;
}

// ---------------- scatter + unpatchify + LN1 + residual + LN2 (shuffle reductions) ----------------
__global__ __launch_bounds__(384) void scatter_ln_kernel(
    const float* __restrict__ x, const float* __restrict__ mpout, const float* __restrict__ B,
    const float* __restrict__ z, const int* __restrict__ isfg, const int* __restrict__ pos,
    const float* __restrict__ n1w, const float* __restrict__ n1b,
    const float* __restrict__ n2w, const float* __restrict__ n2b,
    float* __restrict__ x_mid, ushort* __restrict__ hnorm_bf) {
    int l = blockIdx.x, c = threadIdx.x;
    int wid = c >> 6, lane = c & 63;
    int hh = l / HS, ww = l % HS;
    int p = (hh >> 1) * 28 + (ww >> 1);
    int t = ((hh & 1) << 1) | (ww & 1);
    float v;
    if (isfg[p]) v = mpout[(long long)(1 + pos[p] * 4 + t) * DIM + c];
    else v = B[(long long)(pos[p] * 4 + t) * DIM + c] + z[c];
    __shared__ float r0[8], r1[8], r2[8], r3[8];
    float s1 = v, s2 = v * v;
    #pragma unroll
    for (int off = 32; off >= 1; off >>= 1) { s1 += __shfl_xor(s1, off); s2 += __shfl_xor(s2, off); }
    if (lane == 0) { r0[wid] = s1; r1[wid] = s2; }
    __syncthreads();
    float mean = (r0[0] + r0[1] + r0[2] + r0[3] + r0[4] + r0[5]) / (float)DIM;
    float var = (r1[0] + r1[1] + r1[2] + r1[3] + r1[4] + r1[5]) / (float)DIM - mean * mean;
    float xm = x[(long long)l * DIM + c] + (v - mean) * rsqrtf(var + EPSV) * n1w[c] + n1b[c];
    x_mid[(long long)l * DIM + c] = xm;
    s1 = xm; s2 = xm * xm;
    #pragma unroll
    for (int off = 32; off >= 1; off >>= 1) { s1 += __shfl_xor(s1, off); s2 += __shfl_xor(s2, off); }
    if (lane == 0) { r2[wid] = s1; r3[wid] = s2; }
    __syncthreads();
    float m2 = (r2[0] + r2[1] + r2[2] + r2[3] + r2[4] + r2[5]) / (float)DIM;
    float v2 = (r3[0] + r3[1] + r3[2] + r3[3] + r3[4] + r3[5]) / (float)DIM - m2 * m2;
    hnorm_bf[(long long)l * DIM + c] = f2b((xm - m2) * rsqrtf(v2 + EPSV) * n2w[c] + n2b[c]);
}

__global__ void copy_qa2_kernel(const float* __restrict__ mp, float* __restrict__ dst) {
    dst[threadIdx.x] = mp[threadIdx.x];
}

extern "C" void kernel_launch(void* const* d_in, const int* in_sizes, int n_in,
                              void* d_out, int out_size, void* d_ws, size_t ws_size,
                              hipStream_t stream) {
    const float* x       = (const float*)d_in[0];
    const float* qa      = (const float*)d_in[1];
    const float* conv_w  = (const float*)d_in[2];
    const float* conv_b  = (const float*)d_in[3];
    const float* n1w     = (const float*)d_in[4];
    const float* n1b     = (const float*)d_in[5];
    const float* n2w     = (const float*)d_in[6];
    const float* n2b     = (const float*)d_in[7];
    const float* qkv_w   = (const float*)d_in[8];
    const float* qkv_b   = (const float*)d_in[9];
    const float* mproj_w = (const float*)d_in[10];
    const float* mproj_b = (const float*)d_in[11];
    const float* ap1_w   = (const float*)d_in[12];
    const float* ap1_b   = (const float*)d_in[13];
    const float* ap2_w   = (const float*)d_in[14];
    const float* ap2_b   = (const float*)d_in[15];
    const float* kv_w    = (const float*)d_in[16];
    const float* kv_b    = (const float*)d_in[17];
    const float* sp1_w   = (const float*)d_in[18];
    const float* sp1_b   = (const float*)d_in[19];
    const float* sp2_w   = (const float*)d_in[20];
    const float* sp2_b   = (const float*)d_in[21];
    const float* pn_w    = (const float*)d_in[22];
    const float* pn_b    = (const float*)d_in[23];
    const float* fc1_w   = (const float*)d_in[24];
    const float* fc1_b   = (const float*)d_in[25];
    const float* fc2_w   = (const float*)d_in[26];
    const float* fc2_b   = (const float*)d_in[27];
    float* out = (float*)d_out;
    float* ws  = (float*)d_ws;

    // ---- workspace layout (float offsets) ----
    const long long X1_OFF    = 0;           // 1,204,224 f (x1 fp32; later qkvb_bf 1,807,488 u16)
    const long long BMAT_OFF  = 1204224;     // 602,112 f
    const long long S_OFF     = 1806336;     // 14,770,566 f (S/A2 fp32; later kv_out/hnorm/hact)
    const long long MPOUT_OFF = 16576912;    // 602,496 f (first Xmsa_bf 602,496 u16)
    const long long XMID_OFF  = 17179408;    // 1,204,224 f (first Bmat_bf + attn_bf)
    const long long WBF_OFF   = 18383632;    // 1,032,192 f = 2,064,384 u16
    const long long MEANS_OFF = 19415824;
    const long long X1H_OFF   = 19416608;
    const long long Z_OFF     = 19416992;
    const long long FLAGS_OFF = 19417376;
    const long long ISFG_OFF  = 19418160;
    const long long POS_OFF   = 19418944;
    const long long FGMAP_OFF = 19419728;
    const long long BGMAP_OFF = 19420120;

    float*  x1_arr  = ws + X1_OFF;
    float*  Bmat    = ws + BMAT_OFF;
    float*  Sbuf    = ws + S_OFF;
    float*  mpout   = ws + MPOUT_OFF;
    float*  xmid    = ws + XMID_OFF;
    float*  means   = ws + MEANS_OFF;
    float*  x1h     = ws + X1H_OFF;
    float*  zvec    = ws + Z_OFF;
    int*    flags   = (int*)(ws + FLAGS_OFF);
    int*    isfg    = (int*)(ws + ISFG_OFF);
    int*    pos     = (int*)(ws + POS_OFF);
    int*    fgmap   = (int*)(ws + FGMAP_OFF);
    int*    bgmap   = (int*)(ws + BGMAP_OFF);

    ushort* qkvb_bf = (ushort*)(ws + X1_OFF);            // after gather
    ushort* Xmsa_bf = (ushort*)(ws + MPOUT_OFF);         // dead before mproj writes mpout
    ushort* Bmat_bf = (ushort*)(ws + XMID_OFF);          // dead before scatter writes xmid
    ushort* attn_bf = (ushort*)(ws + XMID_OFF + 301056); // dead before scatter writes xmid
    float*  kv_out  = ws + S_OFF;                        // S dead after PV
    ushort* hnorm_bf= (ushort*)(ws + S_OFF + 1204224);
    ushort* hact_bf = (ushort*)(ws + S_OFF + 1806336);

    ushort* wbf     = (ushort*)(ws + WBF_OFF);
    ushort* qkvw_bf  = wbf;
    ushort* mprojw_bf= wbf + 442368;
    ushort* kvw_bf   = wbf + 589824;
    ushort* fc1w_bf  = wbf + 884736;
    ushort* fc2w_bf  = wbf + 1474560;

    // ---- weight conversion ----
    {
        CvtSeg s0{qkv_w, qkvw_bf, 442368};
        CvtSeg s1{mproj_w, mprojw_bf, 147456};
        CvtSeg s2{kv_w, kvw_bf, 294912};
        CvtSeg s3{fc1_w, fc1w_bf, 589824};
        CvtSeg s4{fc2_w, fc2w_bf, 589824};
        dim3 g(288, 5, 1);
        cvt_kernel<<<g, 256, 0, stream>>>(s0, s1, s2, s3, s4);
    }

    conv_kernel<<<LPIX, 384, 0, stream>>>(x, conv_w, conv_b, x1_arr);
    means_kernel<<<NPATCH, 256, 0, stream>>>(x1_arr, means);
    partition_flags_kernel<<<4, 256, 0, stream>>>(means, flags);
    partition_compact_kernel<<<1, 256, 0, stream>>>(flags, isfg, pos, fgmap, bgmap);
    gather_kernel<<<SEQ + BROWS, 384, 0, stream>>>(x1_arr, qa, fgmap, bgmap, Xmsa_bf, Bmat, Bmat_bf);

    { // qkv: (1569x384)bf16 @ (1152x384)^T -> bf16
        dim3 g(9, 13, 1);
        mgemm<128,1,0,1,0><<<g, 256, 0, stream>>>(Xmsa_bf, DIM, 0, qkvw_bf, DIM, 0, qkv_b,
                                                  nullptr, 0, qkvb_bf, 1152, 0, SEQ, 1152, DIM, 1.f);
    }
    { // S[h] = SCALE * q @ k^T -> fp32, batched over heads
        dim3 g(13, 13, 6);
        mgemm<128,1,0,0,0><<<g, 256, 0, stream>>>(qkvb_bf, 1152, 64, qkvb_bf + 384, 1152, 64, nullptr,
                                                  nullptr, 0, Sbuf, SEQ, (long long)SS, SEQ, SEQ, HD, SCALE);
    }
    modattn_kernel<<<SEQ, 384, 0, stream>>>(Sbuf, ap1_w, ap1_b, ap2_w, ap2_b);
    { // PV: attn_bf[h] = A2[h](fp32) @ V[h](bf16 KxN)
        dim3 g(1, 13, 6);
        mgemm<64,0,0,1,1><<<g, 256, 0, stream>>>(Sbuf, SEQ, (long long)SS, qkvb_bf + 768, 1152, 64, nullptr,
                                                 nullptr, 0, attn_bf, DIM, 64, SEQ, HD, SEQ, 1.f);
    }
    { // mproj -> fp32 mpout
        dim3 g(3, 13, 1);
        mgemm<128,1,0,0,0><<<g, 256, 0, stream>>>(attn_bf, DIM, 0, mprojw_bf, DIM, 0, mproj_b,
                                                  nullptr, 0, mpout, DIM, 0, SEQ, DIM, DIM, 1.f);
    }
    { // kv -> fp32 kv_out
        dim3 g(6, 13, 1);
        mgemm<128,1,0,0,0><<<g, 256, 0, stream>>>(Bmat_bf, DIM, 0, kvw_bf, DIM, 0, kv_b,
                                                  nullptr, 0, kv_out, 768, 0, BROWS, 768, DIM, 1.f);
    }
    sqa_attn_kernel<<<HEADS, 256, 0, stream>>>(kv_out, mpout /* row 0 = qa2 */, x1h);
    sqa_mlp_kernel<<<1, 384, 0, stream>>>(x1h, sp1_w, sp1_b, pn_w, pn_b, sp2_w, sp2_b, zvec);
    scatter_ln_kernel<<<LPIX, 384, 0, stream>>>(x, mpout, Bmat, zvec, isfg, pos,
                                                n1w, n1b, n2w, n2b, xmid, hnorm_bf);
    { // fc1 + silu -> bf16
        dim3 g(12, 25, 1);
        mgemm<128,1,1,1,0><<<g, 256, 0, stream>>>(hnorm_bf, DIM, 0, fc1w_bf, DIM, 0, fc1_b,
                                                  nullptr, 0, hact_bf, HID, 0, LPIX, HID, DIM, 1.f);
    }
    { // fc2 + residual -> out fp32
        dim3 g(3, 25, 1);
        mgemm<128,1,0,0,0><<<g, 256, 0, stream>>>(hact_bf, HID, 0, fc2w_bf, HID, 0, fc2_b,
                                                  xmid, DIM, out, DIM, 0, LPIX, DIM, HID, 1.f);
    }
    copy_qa2_kernel<<<1, 384, 0, stream>>>(mpout, out + (long long)LPIX * DIM);
}

// Round 3
// 623.263 us; speedup vs baseline: 2.5941x; 1.8631x over previous
//
#include <hip/hip_runtime.h>
#include <hip/hip_bf16.h>

#define DIM 384
#define HEADS 6
#define HD 64
#define LPIX 3136
#define HS 56
#define NPATCH 784
#define NF 392
#define SEQ 1569          // 1 + 392*4
#define BROWS 1568
#define HEXP 24
#define PR 96
#define HID 1536
#define SCALE 0.125f
#define EPSV 1e-5f
#define KPAD 1576         // SEQ padded to multiple of 8
#define QSTR 9456         // 6*KPAD, per-q row stride of S/A2 (bf16)

typedef short short8v __attribute__((ext_vector_type(8)));
typedef float f32x4 __attribute__((ext_vector_type(4)));
typedef unsigned short ushort;

__device__ __forceinline__ ushort f2b(float f) {
    __hip_bfloat16 h = __float2bfloat16(f);
    return reinterpret_cast<ushort&>(h);
}
__device__ __forceinline__ float b2f(ushort u) {
    unsigned int ui = ((unsigned int)u) << 16;
    return __uint_as_float(ui);
}

// ---------------- weight fp32 -> bf16 conversion (5 segments in one kernel) ----------------
struct CvtSeg { const float* s; ushort* d; int n; };
__global__ __launch_bounds__(256) void cvt_kernel(CvtSeg a, CvtSeg b, CvtSeg c, CvtSeg d, CvtSeg e) {
    CvtSeg seg;
    switch (blockIdx.y) { case 0: seg = a; break; case 1: seg = b; break; case 2: seg = c; break;
                          case 3: seg = d; break; default: seg = e; break; }
    int idx = (blockIdx.x * 256 + threadIdx.x) * 8;
    if (idx >= seg.n) return;
    float4 f0 = *reinterpret_cast<const float4*>(seg.s + idx);
    float4 f1 = *reinterpret_cast<const float4*>(seg.s + idx + 4);
    ushort u[8] = { f2b(f0.x), f2b(f0.y), f2b(f0.z), f2b(f0.w),
                    f2b(f1.x), f2b(f1.y), f2b(f1.z), f2b(f1.w) };
    *reinterpret_cast<uint4*>(seg.d + idx) = *reinterpret_cast<uint4*>(u);
}

// ---------------- conv (depthwise 3x3 + bias + residual), writes patch-token layout ----------------
__global__ __launch_bounds__(384) void conv_kernel(const float* __restrict__ x,
                                                   const float* __restrict__ cw,
                                                   const float* __restrict__ cb,
                                                   float* __restrict__ x1) {
    int l = blockIdx.x, c = threadIdx.x;
    int hh = l / HS, ww = l % HS;
    float acc = x[(long)l * DIM + c] + cb[c];
    #pragma unroll
    for (int kh = 0; kh < 3; kh++) {
        int h2 = hh + kh - 1;
        if (h2 < 0 || h2 >= HS) continue;
        #pragma unroll
        for (int kw = 0; kw < 3; kw++) {
            int w2 = ww + kw - 1;
            if (w2 < 0 || w2 >= HS) continue;
            acc += x[((long)h2 * HS + w2) * DIM + c] * cw[c * 9 + kh * 3 + kw];
        }
    }
    int p = (hh >> 1) * 28 + (ww >> 1);
    int t = ((hh & 1) << 1) | (ww & 1);
    x1[(long)(p * 4 + t) * DIM + c] = acc;
}

// ---------------- per-patch means ----------------
__global__ __launch_bounds__(256) void means_kernel(const float* __restrict__ x1, float* __restrict__ means) {
    int p = blockIdx.x, tid = threadIdx.x;
    __shared__ float red[256];
    float s = 0.f;
    for (int i = tid; i < 1536; i += 256) s += x1[(long)p * 1536 + i];
    red[tid] = s; __syncthreads();
    for (int k = 128; k > 0; k >>= 1) { if (tid < k) red[tid] += red[tid + k]; __syncthreads(); }
    if (tid == 0) means[p] = red[0] / 1536.f;
}

// ---------------- rank flags (parallel over patches) ----------------
__global__ __launch_bounds__(256) void partition_flags_kernel(const float* __restrict__ means, int* __restrict__ flags) {
    int p = blockIdx.x * 256 + threadIdx.x;
    if (p >= NPATCH) return;
    float m = means[p];
    int rank = 0;
    for (int q = 0; q < NPATCH; q++) {
        float mq = means[q];
        rank += (mq > m) || (mq == m && q < p);
    }
    flags[p] = (rank < NF) ? 1 : 0;
}

// ---------------- compaction: prefix scan over flags ----------------
__global__ __launch_bounds__(256) void partition_compact_kernel(const int* __restrict__ flags, int* __restrict__ isfg,
                                                                int* __restrict__ pos, int* __restrict__ fgmap,
                                                                int* __restrict__ bgmap) {
    __shared__ int f_s[NPATCH];
    __shared__ int scan_s[256];
    int tid = threadIdx.x;
    for (int p = tid; p < NPATCH; p += 256) f_s[p] = flags[p];
    __syncthreads();
    int base = tid * 4, cnt = 0;
    #pragma unroll
    for (int i = 0; i < 4; i++) { int p = base + i; if (p < NPATCH) cnt += f_s[p]; }
    scan_s[tid] = cnt; __syncthreads();
    for (int off = 1; off < 256; off <<= 1) {
        int add = (tid >= off) ? scan_s[tid - off] : 0;
        __syncthreads();
        scan_s[tid] += add;
        __syncthreads();
    }
    int run = scan_s[tid] - cnt;
    for (int i = 0; i < 4; i++) {
        int p = base + i;
        if (p >= NPATCH) break;
        int f = f_s[p];
        if (f) { isfg[p] = 1; pos[p] = run; fgmap[run] = p; run++; }
        else   { isfg[p] = 0; pos[p] = p - run; bgmap[p - run] = p; }
    }
}

// ---------------- gather foreground (with qa row 0) and background ----------------
__global__ __launch_bounds__(384) void gather_kernel(const float* __restrict__ x1, const float* __restrict__ qa,
                                                     const int* __restrict__ fgmap, const int* __restrict__ bgmap,
                                                     ushort* __restrict__ Xmsa_bf, float* __restrict__ B,
                                                     ushort* __restrict__ B_bf) {
    int c = threadIdx.x;
    int bid = blockIdx.x;
    if (bid == 0) { Xmsa_bf[c] = f2b(qa[c]); return; }
    if (bid <= BROWS) {
        int r = bid - 1;
        int src = fgmap[r >> 2] * 4 + (r & 3);
        Xmsa_bf[(long)bid * DIM + c] = f2b(x1[(long)src * DIM + c]);
    } else {
        int r = bid - SEQ;
        int src = bgmap[r >> 2] * 4 + (r & 3);
        float v = x1[(long)src * DIM + c];
        B[(long)r * DIM + c] = v;
        B_bf[(long)r * DIM + c] = f2b(v);
    }
}

// ---------------- bf16 MFMA GEMM ----------------
// C = alpha * A @ op(B) + bias (+silu) (+resid). A is bf16.
// OPB=1: B is [N][K] bf16 (A@B^T). OPB=0: B is [K][N] bf16 (requires BN=64).
template<int BM, int BN, int OPB, int ACT, int OUTBF>
__global__ __launch_bounds__(256) void mgemm(
    const ushort* __restrict__ A, int lda, long long sA,
    const ushort* __restrict__ B, int ldb, long long sB,
    const float* __restrict__ bias, const float* __restrict__ resid, int ldr,
    void* __restrict__ Cv, int ldc, long long sC,
    int M, int N, int K, float alpha) {
    constexpr int BK = 32, LDT = BK + 8;
    constexpr int WR = (BM == 128 && BN == 128) ? 2 : ((BM == 128) ? 4 : 2);
    constexpr int WC = 4 / WR;
    constexpr int MFR = BM / WR / 16;
    constexpr int NFR = BN / WC / 16;
    __shared__ ushort As[BM * LDT];
    __shared__ ushort Bs[BN * LDT];
    int tid = threadIdx.x;
    int wid = tid >> 6, lane = tid & 63;
    int m0 = blockIdx.y * BM, n0 = blockIdx.x * BN;
    int bz = blockIdx.z;
    A += (long long)bz * sA;
    B += (long long)bz * sB;
    int wm = (wid / WC) * (BM / WR);
    int wn = (wid % WC) * (BN / WC);
    f32x4 acc[MFR][NFR];
    #pragma unroll
    for (int mi = 0; mi < MFR; mi++)
        #pragma unroll
        for (int ni = 0; ni < NFR; ni++) acc[mi][ni] = (f32x4){0.f, 0.f, 0.f, 0.f};

    for (int k0 = 0; k0 < K; k0 += BK) {
        { // ---- stage A: BM x 32 ----
            constexpr int CHA = BM * 4 / 256;
            #pragma unroll
            for (int t = 0; t < CHA; t++) {
                int chunk = tid + t * 256;
                int row = chunk >> 2, part = chunk & 3;
                int gm = m0 + row, gk = k0 + part * 8;
                ushort* dst = &As[row * LDT + part * 8];
                if (gm < M && gk + 8 <= K) {
                    *reinterpret_cast<uint4*>(dst) =
                        *reinterpret_cast<const uint4*>(&A[(long long)gm * lda + gk]);
                } else {
                    #pragma unroll
                    for (int i = 0; i < 8; i++) {
                        int k = gk + i;
                        dst[i] = (gm < M && k < K) ? A[(long long)gm * lda + k] : (ushort)0;
                    }
                }
            }
        }
        if (OPB == 1) { // ---- stage B: BN x 32 from [N][K] ----
            constexpr int CHB = BN * 4 / 256;
            #pragma unroll
            for (int t = 0; t < CHB; t++) {
                int chunk = tid + t * 256;
                int row = chunk >> 2, part = chunk & 3;
                int gn = n0 + row, gk = k0 + part * 8;
                ushort* dst = &Bs[row * LDT + part * 8];
                if (gn < N && gk + 8 <= K) {
                    *reinterpret_cast<uint4*>(dst) =
                        *reinterpret_cast<const uint4*>(&B[(long long)gn * ldb + gk]);
                } else {
                    #pragma unroll
                    for (int i = 0; i < 8; i++) {
                        int k = gk + i;
                        dst[i] = (gn < N && k < K) ? B[(long long)gn * ldb + k] : (ushort)0;
                    }
                }
            }
        } else { // ---- stage B: 32 x 64 from [K][N], transpose ----
            int kr = tid >> 3, nn = (tid & 7) * 8;
            int gk = k0 + kr;
            ushort vals[8];
            if (gk < K && n0 + nn + 8 <= N) {
                *reinterpret_cast<uint4*>(vals) =
                    *reinterpret_cast<const uint4*>(&B[(long long)gk * ldb + n0 + nn]);
            } else {
                #pragma unroll
                for (int i = 0; i < 8; i++) {
                    int gn = n0 + nn + i;
                    vals[i] = (gk < K && gn < N) ? B[(long long)gk * ldb + gn] : (ushort)0;
                }
            }
            #pragma unroll
            for (int i = 0; i < 8; i++) Bs[(nn + i) * LDT + kr] = vals[i];
        }
        __syncthreads();
        short8v a[MFR], b[NFR];
        #pragma unroll
        for (int mi = 0; mi < MFR; mi++)
            a[mi] = *reinterpret_cast<const short8v*>(&As[(wm + mi * 16 + (lane & 15)) * LDT + (lane >> 4) * 8]);
        #pragma unroll
        for (int ni = 0; ni < NFR; ni++)
            b[ni] = *reinterpret_cast<const short8v*>(&Bs[(wn + ni * 16 + (lane & 15)) * LDT + (lane >> 4) * 8]);
        #pragma unroll
        for (int mi = 0; mi < MFR; mi++)
            #pragma unroll
            for (int ni = 0; ni < NFR; ni++)
                acc[mi][ni] = __builtin_amdgcn_mfma_f32_16x16x32_bf16(a[mi], b[ni], acc[mi][ni], 0, 0, 0);
        __syncthreads();
    }
    ushort* C16 = (ushort*)Cv;
    float* C32 = (float*)Cv;
    #pragma unroll
    for (int mi = 0; mi < MFR; mi++) {
        #pragma unroll
        for (int j = 0; j < 4; j++) {
            int gm = m0 + wm + mi * 16 + (lane >> 4) * 4 + j;
            if (gm >= M) continue;
            #pragma unroll
            for (int ni = 0; ni < NFR; ni++) {
                int gn = n0 + wn + ni * 16 + (lane & 15);
                if (gn >= N) continue;
                float v = acc[mi][ni][j] * alpha;
                if (bias) v += bias[gn];
                if (ACT == 1) v = v / (1.f + __expf(-v));
                if (resid) v += resid[(long long)gm * ldr + gn];
                long long ci = bz * sC + (long long)gm * ldc + gn;
                if (OUTBF) C16[ci] = f2b(v); else C32[ci] = v;
            }
        }
    }
}

// ---------------- modulated attention: S[q][h][KPAD] bf16, in place, batched reductions ----------------
__global__ __launch_bounds__(512, 2) void modattn_kernel(
    ushort* __restrict__ S,
    const float* __restrict__ ap1_w, const float* __restrict__ ap1_b,
    const float* __restrict__ ap2_w, const float* __restrict__ ap2_b) {
    int q = blockIdx.x, tid = threadIdx.x;
    int wid = tid >> 6, lane = tid & 63;
    __shared__ float w1s[144], w2s[144], b1s[24], b2s[6];
    __shared__ float red[8][24];
    __shared__ float fin[24];
    if (tid < 144) { w1s[tid] = ap1_w[tid]; w2s[tid] = ap2_w[tid]; }
    if (tid < 24) b1s[tid] = ap1_b[tid];
    if (tid < 6)  b2s[tid] = ap2_b[tid];
    __syncthreads();
    ushort* Sq = S + (long long)q * QSTR;
    // load S columns (each thread owns k = tid + j*512)
    float sreg[4][6];
    #pragma unroll
    for (int j = 0; j < 4; j++) {
        int k = tid + j * 512;
        #pragma unroll
        for (int h = 0; h < 6; h++)
            sreg[j][h] = (k < SEQ) ? b2f(Sq[h * KPAD + k]) : 0.f;
    }
    // a1 = W1 @ s + b1, running max over own k's
    float a1[4][24];
    float r24[24];
    #pragma unroll
    for (int e = 0; e < 24; e++) r24[e] = -3.4e38f;
    #pragma unroll
    for (int j = 0; j < 4; j++) {
        int k = tid + j * 512;
        bool v = k < SEQ;
        #pragma unroll
        for (int e = 0; e < 24; e++) {
            float a = b1s[e];
            #pragma unroll
            for (int h = 0; h < 6; h++) a = fmaf(sreg[j][h], w1s[e * 6 + h], a);
            a1[j][e] = a;
            if (v) r24[e] = fmaxf(r24[e], a);
        }
    }
    // batched wave max reduce (24 independent butterflies)
    #pragma unroll
    for (int e = 0; e < 24; e++) {
        float v = r24[e];
        #pragma unroll
        for (int off = 32; off >= 1; off >>= 1) v = fmaxf(v, __shfl_xor(v, off));
        r24[e] = v;
    }
    if (lane == 0) {
        #pragma unroll
        for (int e = 0; e < 24; e++) red[wid][e] = r24[e];
    }
    __syncthreads();
    if (tid < 24) {
        float v = red[0][tid];
        #pragma unroll
        for (int w = 1; w < 8; w++) v = fmaxf(v, red[w][tid]);
        fin[tid] = v;
    }
    __syncthreads();
    // exp + running sum
    #pragma unroll
    for (int e = 0; e < 24; e++) r24[e] = 0.f;
    #pragma unroll
    for (int j = 0; j < 4; j++) {
        int k = tid + j * 512;
        bool v = k < SEQ;
        #pragma unroll
        for (int e = 0; e < 24; e++) {
            float p = v ? __expf(a1[j][e] - fin[e]) : 0.f;
            a1[j][e] = p;
            r24[e] += p;
        }
    }
    #pragma unroll
    for (int e = 0; e < 24; e++) {
        float v = r24[e];
        #pragma unroll
        for (int off = 32; off >= 1; off >>= 1) v += __shfl_xor(v, off);
        r24[e] = v;
    }
    __syncthreads();   // all fin reads (exp loop) done before rewrite
    if (lane == 0) {
        #pragma unroll
        for (int e = 0; e < 24; e++) red[wid][e] = r24[e];
    }
    __syncthreads();
    if (tid < 24) {
        float v = red[0][tid];
        #pragma unroll
        for (int w = 1; w < 8; w++) v += red[w][tid];
        fin[tid] = 1.f / v;
    }
    __syncthreads();
    // a2 = W2 @ (p * inv) + b2, write back in place (bf16)
    #pragma unroll
    for (int j = 0; j < 4; j++) {
        int k = tid + j * 512;
        if (k >= SEQ) continue;
        float a2[6];
        #pragma unroll
        for (int h = 0; h < 6; h++) a2[h] = b2s[h];
        #pragma unroll
        for (int e = 0; e < 24; e++) {
            float p = a1[j][e] * fin[e];
            #pragma unroll
            for (int h = 0; h < 6; h++) a2[h] = fmaf(p, w2s[h * 24 + e], a2[h]);
        }
        #pragma unroll
        for (int h = 0; h < 6; h++) Sq[h * KPAD + k] = f2b(a2[h]);
    }
}

// ---------------- single-query attention pooling (per head) ----------------
__global__ __launch_bounds__(256) void sqa_attn_kernel(const float* __restrict__ kv, const float* __restrict__ qa2,
                                                       float* __restrict__ x1h) {
    int h = blockIdx.x, tid = threadIdx.x;
    __shared__ float q_s[HD];
    __shared__ float l_s[BROWS];
    __shared__ float red[256];
    if (tid < HD) q_s[tid] = qa2[h * HD + tid];
    __syncthreads();
    float lmax = -1e30f;
    for (int s = tid; s < BROWS; s += 256) {
        const float* krow = kv + (long long)s * 768 + h * HD;
        float d = 0.f;
        for (int i = 0; i < HD; i++) d += krow[i] * q_s[i];
        d *= SCALE; l_s[s] = d; lmax = fmaxf(lmax, d);
    }
    red[tid] = lmax; __syncthreads();
    for (int s = 128; s > 0; s >>= 1) { if (tid < s) red[tid] = fmaxf(red[tid], red[tid + s]); __syncthreads(); }
    float gmax = red[0]; __syncthreads();
    float lsum = 0.f;
    for (int s = tid; s < BROWS; s += 256) { float p = __expf(l_s[s] - gmax); l_s[s] = p; lsum += p; }
    red[tid] = lsum; __syncthreads();
    for (int s = 128; s > 0; s >>= 1) { if (tid < s) red[tid] += red[tid + s]; __syncthreads(); }
    float inv = 1.f / red[0]; __syncthreads();
    int d = tid & 63, g = tid >> 6;
    float acc = 0.f;
    for (int s = g; s < BROWS; s += 4) acc += l_s[s] * kv[(long long)s * 768 + 384 + h * HD + d];
    red[tid] = acc; __syncthreads();
    if (tid < HD) x1h[h * HD + d] = (red[d] + red[64 + d] + red[128 + d] + red[192 + d]) * inv;
}

// ---------------- sqa mlp: sp1 -> LN -> relu -> sp2 ----------------
__global__ __launch_bounds__(384) void sqa_mlp_kernel(const float* __restrict__ x1h,
                                                      const float* __restrict__ sp1_w, const float* __restrict__ sp1_b,
                                                      const float* __restrict__ pn_w, const float* __restrict__ pn_b,
                                                      const float* __restrict__ sp2_w, const float* __restrict__ sp2_b,
                                                      float* __restrict__ z) {
    __shared__ float y_s[PR];
    __shared__ float x_s[DIM];
    __shared__ float mv[2];
    int tid = threadIdx.x;
    x_s[tid] = x1h[tid];
    __syncthreads();
    if (tid < PR) {
        float a = sp1_b[tid];
        for (int c = 0; c < DIM; c++) a += sp1_w[tid * DIM + c] * x_s[c];
        y_s[tid] = a;
    }
    __syncthreads();
    if (tid == 0) {
        float m = 0.f; for (int i = 0; i < PR; i++) m += y_s[i]; m /= (float)PR;
        float v = 0.f; for (int i = 0; i < PR; i++) { float d = y_s[i] - m; v += d * d; } v /= (float)PR;
        mv[0] = m; mv[1] = rsqrtf(v + EPSV);
    }
    __syncthreads();
    if (tid < PR) {
        float yn = (y_s[tid] - mv[0]) * mv[1] * pn_w[tid] + pn_b[tid];
        y_s[tid] = fmaxf(yn, 0.f);
    }
    __syncthreads();
    float a = sp2_b[tid];
    for (int j = 0; j < PR; j++) a += sp2_w[tid * PR + j] * y_s[j];
    z[tid] = a;
}

// ---------------- scatter + unpatchify + LN1 + residual + LN2 (shuffle reductions) ----------------
__global__ __launch_bounds__(384) void scatter_ln_kernel(
    const float* __restrict__ x, const float* __restrict__ mpout, const float* __restrict__ B,
    const float* __restrict__ z, const int* __restrict__ isfg, const int* __restrict__ pos,
    const float* __restrict__ n1w, const float* __restrict__ n1b,
    const float* __restrict__ n2w, const float* __restrict__ n2b,
    float* __restrict__ x_mid, ushort* __restrict__ hnorm_bf) {
    int l = blockIdx.x, c = threadIdx.x;
    int wid = c >> 6, lane = c & 63;
    int hh = l / HS, ww = l % HS;
    int p = (hh >> 1) * 28 + (ww >> 1);
    int t = ((hh & 1) << 1) | (ww & 1);
    float v;
    if (isfg[p]) v = mpout[(long long)(1 + pos[p] * 4 + t) * DIM + c];
    else v = B[(long long)(pos[p] * 4 + t) * DIM + c] + z[c];
    __shared__ float r0[8], r1[8], r2[8], r3[8];
    float s1 = v, s2 = v * v;
    #pragma unroll
    for (int off = 32; off >= 1; off >>= 1) { s1 += __shfl_xor(s1, off); s2 += __shfl_xor(s2, off); }
    if (lane == 0) { r0[wid] = s1; r1[wid] = s2; }
    __syncthreads();
    float mean = (r0[0] + r0[1] + r0[2] + r0[3] + r0[4] + r0[5]) / (float)DIM;
    float var = (r1[0] + r1[1] + r1[2] + r1[3] + r1[4] + r1[5]) / (float)DIM - mean * mean;
    float xm = x[(long long)l * DIM + c] + (v - mean) * rsqrtf(var + EPSV) * n1w[c] + n1b[c];
    x_mid[(long long)l * DIM + c] = xm;
    s1 = xm; s2 = xm * xm;
    #pragma unroll
    for (int off = 32; off >= 1; off >>= 1) { s1 += __shfl_xor(s1, off); s2 += __shfl_xor(s2, off); }
    if (lane == 0) { r2[wid] = s1; r3[wid] = s2; }
    __syncthreads();
    float m2 = (r2[0] + r2[1] + r2[2] + r2[3] + r2[4] + r2[5]) / (float)DIM;
    float v2 = (r3[0] + r3[1] + r3[2] + r3[3] + r3[4] + r3[5]) / (float)DIM - m2 * m2;
    hnorm_bf[(long long)l * DIM + c] = f2b((xm - m2) * rsqrtf(v2 + EPSV) * n2w[c] + n2b[c]);
}

__global__ void copy_qa2_kernel(const float* __restrict__ mp, float* __restrict__ dst) {
    dst[threadIdx.x] = mp[threadIdx.x];
}

extern "C" void kernel_launch(void* const* d_in, const int* in_sizes, int n_in,
                              void* d_out, int out_size, void* d_ws, size_t ws_size,
                              hipStream_t stream) {
    const float* x       = (const float*)d_in[0];
    const float* qa      = (const float*)d_in[1];
    const float* conv_w  = (const float*)d_in[2];
    const float* conv_b  = (const float*)d_in[3];
    const float* n1w     = (const float*)d_in[4];
    const float* n1b     = (const float*)d_in[5];
    const float* n2w     = (const float*)d_in[6];
    const float* n2b     = (const float*)d_in[7];
    const float* qkv_w   = (const float*)d_in[8];
    const float* qkv_b   = (const float*)d_in[9];
    const float* mproj_w = (const float*)d_in[10];
    const float* mproj_b = (const float*)d_in[11];
    const float* ap1_w   = (const float*)d_in[12];
    const float* ap1_b   = (const float*)d_in[13];
    const float* ap2_w   = (const float*)d_in[14];
    const float* ap2_b   = (const float*)d_in[15];
    const float* kv_w    = (const float*)d_in[16];
    const float* kv_b    = (const float*)d_in[17];
    const float* sp1_w   = (const float*)d_in[18];
    const float* sp1_b   = (const float*)d_in[19];
    const float* sp2_w   = (const float*)d_in[20];
    const float* sp2_b   = (const float*)d_in[21];
    const float* pn_w    = (const float*)d_in[22];
    const float* pn_b    = (const float*)d_in[23];
    const float* fc1_w   = (const float*)d_in[24];
    const float* fc1_b   = (const float*)d_in[25];
    const float* fc2_w   = (const float*)d_in[26];
    const float* fc2_b   = (const float*)d_in[27];
    float* out = (float*)d_out;
    float* ws  = (float*)d_ws;

    // ---- workspace layout (float offsets), same footprint as round 2 ----
    const long long X1_OFF    = 0;           // x1 fp32 (1,204,224 f); later qkvb_bf (903,744 f)
    const long long BMAT_OFF  = 1204224;     // Bmat fp32 602,112 f
    const long long S_OFF     = 1806336;     // S16/A2 bf16 in place (7,418,232 f); later kv_out/hnorm/hact
    const long long MPOUT_OFF = 16576912;    // mpout fp32 602,496 f (first Xmsa_bf)
    const long long XMID_OFF  = 17179408;    // xmid fp32 1,204,224 f (first Bmat_bf + attn_bf)
    const long long WBF_OFF   = 18383632;    // bf16 weights 1,032,192 f
    const long long MEANS_OFF = 19415824;
    const long long X1H_OFF   = 19416608;
    const long long Z_OFF     = 19416992;
    const long long FLAGS_OFF = 19417376;
    const long long ISFG_OFF  = 19418160;
    const long long POS_OFF   = 19418944;
    const long long FGMAP_OFF = 19419728;
    const long long BGMAP_OFF = 19420120;

    float*  x1_arr  = ws + X1_OFF;
    float*  Bmat    = ws + BMAT_OFF;
    float*  mpout   = ws + MPOUT_OFF;
    float*  xmid    = ws + XMID_OFF;
    float*  means   = ws + MEANS_OFF;
    float*  x1h     = ws + X1H_OFF;
    float*  zvec    = ws + Z_OFF;
    int*    flags   = (int*)(ws + FLAGS_OFF);
    int*    isfg    = (int*)(ws + ISFG_OFF);
    int*    pos     = (int*)(ws + POS_OFF);
    int*    fgmap   = (int*)(ws + FGMAP_OFF);
    int*    bgmap   = (int*)(ws + BGMAP_OFF);

    ushort* S16     = (ushort*)(ws + S_OFF);             // [1569][6][KPAD] bf16, S then A2 in place
    ushort* qkvb_bf = (ushort*)(ws + X1_OFF);            // after gather (x1 dead)
    ushort* Xmsa_bf = (ushort*)(ws + MPOUT_OFF);         // dead before mproj writes mpout
    ushort* Bmat_bf = (ushort*)(ws + XMID_OFF);          // dead before scatter writes xmid
    ushort* attn_bf = (ushort*)(ws + XMID_OFF + 301056); // dead before scatter writes xmid
    float*  kv_out  = ws + S_OFF;                        // S16 dead after PV
    ushort* hnorm_bf= (ushort*)(ws + S_OFF + 1204224);
    ushort* hact_bf = (ushort*)(ws + S_OFF + 1806336);

    ushort* wbf      = (ushort*)(ws + WBF_OFF);
    ushort* qkvw_bf  = wbf;
    ushort* mprojw_bf= wbf + 442368;
    ushort* kvw_bf   = wbf + 589824;
    ushort* fc1w_bf  = wbf + 884736;
    ushort* fc2w_bf  = wbf + 1474560;

    { // weight conversion
        CvtSeg s0{qkv_w, qkvw_bf, 442368};
        CvtSeg s1{mproj_w, mprojw_bf, 147456};
        CvtSeg s2{kv_w, kvw_bf, 294912};
        CvtSeg s3{fc1_w, fc1w_bf, 589824};
        CvtSeg s4{fc2_w, fc2w_bf, 589824};
        dim3 g(288, 5, 1);
        cvt_kernel<<<g, 256, 0, stream>>>(s0, s1, s2, s3, s4);
    }

    conv_kernel<<<LPIX, 384, 0, stream>>>(x, conv_w, conv_b, x1_arr);
    means_kernel<<<NPATCH, 256, 0, stream>>>(x1_arr, means);
    partition_flags_kernel<<<4, 256, 0, stream>>>(means, flags);
    partition_compact_kernel<<<1, 256, 0, stream>>>(flags, isfg, pos, fgmap, bgmap);
    gather_kernel<<<SEQ + BROWS, 384, 0, stream>>>(x1_arr, qa, fgmap, bgmap, Xmsa_bf, Bmat, Bmat_bf);

    { // qkv: (1569x384) @ (1152x384)^T -> bf16
        dim3 g(18, 25, 1);
        mgemm<64,64,1,0,1><<<g, 256, 0, stream>>>(Xmsa_bf, DIM, 0, qkvw_bf, DIM, 0, qkv_b,
                                                  nullptr, 0, qkvb_bf, 1152, 0, SEQ, 1152, DIM, 1.f);
    }
    { // S[q][h][k] = SCALE * q@k^T -> bf16, batched heads
        dim3 g(13, 13, 6);
        mgemm<128,128,1,0,1><<<g, 256, 0, stream>>>(qkvb_bf, 1152, 64, qkvb_bf + 384, 1152, 64, nullptr,
                                                    nullptr, 0, S16, QSTR, (long long)KPAD, SEQ, SEQ, HD, SCALE);
    }
    modattn_kernel<<<SEQ, 512, 0, stream>>>(S16, ap1_w, ap1_b, ap2_w, ap2_b);
    { // PV: attn_bf[q][h*64+d] = A2[h] @ V[h]
        dim3 g(1, 25, 6);
        mgemm<64,64,0,0,1><<<g, 256, 0, stream>>>(S16, QSTR, (long long)KPAD, qkvb_bf + 768, 1152, 64, nullptr,
                                                  nullptr, 0, attn_bf, DIM, 64, SEQ, HD, SEQ, 1.f);
    }
    { // mproj -> fp32 mpout
        dim3 g(6, 25, 1);
        mgemm<64,64,1,0,0><<<g, 256, 0, stream>>>(attn_bf, DIM, 0, mprojw_bf, DIM, 0, mproj_b,
                                                  nullptr, 0, mpout, DIM, 0, SEQ, DIM, DIM, 1.f);
    }
    { // kv -> fp32
        dim3 g(12, 25, 1);
        mgemm<64,64,1,0,0><<<g, 256, 0, stream>>>(Bmat_bf, DIM, 0, kvw_bf, DIM, 0, kv_b,
                                                  nullptr, 0, kv_out, 768, 0, BROWS, 768, DIM, 1.f);
    }
    sqa_attn_kernel<<<HEADS, 256, 0, stream>>>(kv_out, mpout /* row 0 = qa2 */, x1h);
    sqa_mlp_kernel<<<1, 384, 0, stream>>>(x1h, sp1_w, sp1_b, pn_w, pn_b, sp2_w, sp2_b, zvec);
    scatter_ln_kernel<<<LPIX, 384, 0, stream>>>(x, mpout, Bmat, zvec, isfg, pos,
                                                n1w, n1b, n2w, n2b, xmid, hnorm_bf);
    { // fc1 + silu -> bf16
        dim3 g(12, 25, 1);
        mgemm<128,128,1,1,1><<<g, 256, 0, stream>>>(hnorm_bf, DIM, 0, fc1w_bf, DIM, 0, fc1_b,
                                                    nullptr, 0, hact_bf, HID, 0, LPIX, HID, DIM, 1.f);
    }
    { // fc2 + residual -> out fp32
        dim3 g(6, 50, 1);
        mgemm<64,64,1,0,0><<<g, 256, 0, stream>>>(hact_bf, HID, 0, fc2w_bf, HID, 0, fc2_b,
                                                  xmid, DIM, out, DIM, 0, LPIX, DIM, HID, 1.f);
    }
    copy_qa2_kernel<<<1, 384, 0, stream>>>(mpout, out + (long long)LPIX * DIM);
}